// Round 3
// baseline (232.479 us; speedup 1.0000x reference)
//
#include <hip/hip_runtime.h>
#include <hip/hip_bf16.h>

// ---------------- constants ----------------
#define BATCH   64
#define LSIG    240000
#define WIN     400
#define SHIFT   160
#define NFR     1498        // 1 + (240000-400)/160
#define NMEL    80
#define NBIN    200         // win/2 ; Nyquist bin has zero bank weight
#define NF      8           // frames per block
#define MAXW    14          // max nonzero mel-bank width (true max 12-13)
#define SPECW   (NBIN + MAXW)

// ---------------- precomputed tables (device globals) ----------------
__device__ float g_win[WIN];                 // Hann (denominator 399), f64-computed
__device__ float g_tw1[11][20][2];           // e^{-2pi i r t1 / 20}
__device__ float g_tw2T[20][NBIN][2];        // e^{-2pi i k t2 / 400}, TRANSPOSED [t2][k]
__device__ int   g_melStart[NMEL];
__device__ float g_melW[NMEL][MAXW];

__global__ void init_tables_kernel() {
    const int tid = threadIdx.x;              // 1 block x 256
    const double PI = 3.14159265358979323846;
    __shared__ double melf[NBIN];
    __shared__ float root[WIN][2];            // e^{-2pi i j/400}

    // 400 f64 sincos total, ~2 per thread (was ~17 per thread)
    for (int j = tid; j < WIN; j += 256) {
        double th = -2.0 * PI * (double)j / 400.0;
        root[j][0] = (float)cos(th);
        root[j][1] = (float)sin(th);
        g_win[j] = (float)(0.5 - 0.5 * cos(2.0 * PI * (double)j / 399.0));
    }
    for (int k = tid; k < NBIN; k += 256)
        melf[k] = 1127.0 * log(1.0 + (40.0 * (double)k) / 700.0);
    __syncthreads();

    for (int i = tid; i < 11 * 20; i += 256) {
        int r = i / 20, t1 = i % 20;
        int j = (20 * r * t1) % 400;
        g_tw1[r][t1][0] = root[j][0];
        g_tw1[r][t1][1] = root[j][1];
    }
    for (int i = tid; i < NBIN * 20; i += 256) {
        int t2 = i / NBIN, k = i - t2 * NBIN;
        int j = (k * t2) % 400;
        g_tw2T[t2][k][0] = root[j][0];
        g_tw2T[t2][k][1] = root[j][1];
    }
    if (tid < NMEL) {
        int m = tid;
        double mlow  = 1127.0 * log(1.0 + 20.0   / 700.0);
        double mhigh = 1127.0 * log(1.0 + 8000.0 / 700.0);
        double d     = (mhigh - mlow) / (double)(NMEL + 1);
        double inv_d = 1.0 / d;
        double left  = mlow + (double)m * d;
        double right = left + 2.0 * d;
        for (int j = 0; j < MAXW; j++) g_melW[m][j] = 0.0f;
        int start = 0; bool found = false;
        for (int k = 0; k < NBIN; k++) {
            double up = (melf[k] - left) * inv_d, down = (right - melf[k]) * inv_d;
            double w = fmax(0.0, fmin(up, down));
            if (w > 0.0) {
                if (!found) { start = k; found = true; }
                int j = k - start;
                if (j < MAXW) g_melW[m][j] = (float)w;
            }
        }
        g_melStart[m] = start;
    }
}

// ---------------- main fbank kernel ----------------
// block: 256 threads, NF consecutive frames of one batch row.
// LDS: [0..3520) S[f][t2][11][2]   [3520..) xseg ALIASED WITH spec
__global__ __launch_bounds__(256, 6)
void fbank_kernel(const float* __restrict__ x, const float* __restrict__ norm,
                  float* __restrict__ out) {
    const int ft = blockIdx.x;
    const int b  = blockIdx.y;
    const int f0 = ft * NF;
    const int nf = min(NF, NFR - f0);

    __shared__ __align__(16) float smem[3520 + NF * SPECW];
    float* Sb   = smem;            // ((f*20 + t2)*11 + r)*2
    float* xseg = smem + 3520;     // 1520 floats
    float* spec = smem + 3520;     // NF*SPECW = 1712 floats (aliases xseg)

    const float* xb = x + (size_t)b * LSIG + (size_t)f0 * SHIFT;
    const int seglen = (nf - 1) * SHIFT + WIN;
    for (int i = threadIdx.x; i < seglen; i += 256) xseg[i] = xb[i];
    __syncthreads();

    // stage 1 (fused preemph+window): 20-point real DFTs over t1, r=0..10
    {
        const int p = threadIdx.x;
        if (p < nf * 20) {
            const int f = p / 20, t2 = p - f * 20;
            const float* xf = xseg + f * SHIFT;
            float yr[20];
#pragma unroll
            for (int t1 = 0; t1 < 20; t1++) {
                int t = t2 + 20 * t1;
                float xc = xf[t];
                float xp = xf[t > 0 ? t - 1 : 0];   // t==0: win==0 -> 0 anyway
                yr[t1] = (xc - 0.97f * xp) * g_win[t];
            }
#pragma unroll
            for (int r = 0; r <= 10; r++) {
                float ar = 0.0f, ai = 0.0f;
#pragma unroll
                for (int t1 = 0; t1 < 20; t1++) {
                    float c = g_tw1[r][t1][0], s = g_tw1[r][t1][1];
                    ar = fmaf(yr[t1], c, ar);
                    ai = fmaf(yr[t1], s, ai);
                }
                *(float2*)(Sb + ((f * 20 + t2) * 11 + r) * 2) = make_float2(ar, ai);
            }
        }
    }
    __syncthreads();

    // stage 2: thread = bin k; outer t2 (2 live twiddle regs), inner f
    // (16 accumulators). Conjugate fold: power invariant under xi -> sgn*xi.
    {
        const int k = threadIdx.x;
        if (k < NBIN) {
            int r = k % 20;
            int rp  = (r > 10) ? 20 - r : r;
            float sg = (r > 10) ? -1.0f : 1.0f;
            float xr[NF], xi[NF];
#pragma unroll
            for (int f = 0; f < NF; f++) { xr[f] = 0.0f; xi[f] = 0.0f; }
            const float2* twp = (const float2*)&g_tw2T[0][k][0];
            for (int t2 = 0; t2 < 20; t2++) {
                float2 tw = twp[t2 * NBIN];          // coalesced across k
                float c = tw.x, s = tw.y * sg;
#pragma unroll
                for (int f = 0; f < NF; f++) {
                    float2 v = *(const float2*)(Sb + ((f * 20 + t2) * 11 + rp) * 2);
                    xr[f] = fmaf(c, v.x, fmaf(-s, v.y, xr[f]));
                    xi[f] = fmaf(s, v.x, fmaf(c,  v.y, xi[f]));
                }
            }
            for (int f = 0; f < nf; f++)
                spec[f * SPECW + k] = fmaf(xr[f], xr[f], xi[f] * xi[f]);
        } else if (k < NBIN + MAXW) {
            for (int f = 0; f < nf; f++) spec[f * SPECW + k] = 0.0f;  // pad taps
        }
    }
    __syncthreads();

    // stage 3: sparse mel + log + normalizer, coalesced store
    const int outs = nf * NMEL;
    for (int o = threadIdx.x; o < outs; o += 256) {
        int f = o / NMEL, m = o - f * NMEL;
        int ks = g_melStart[m];
        const float* sp = spec + f * SPECW + ks;
        float acc = 0.0f;
#pragma unroll
        for (int j = 0; j < MAXW; j++)
            acc = fmaf(g_melW[m][j], sp[j], acc);
        float mel = fmaxf(acc, 2.2204460492503131e-16f);
        float v = logf(mel) * norm[m];
        out[((size_t)b * NFR + (f0 + f)) * NMEL + m] = v;
    }
}

// ---------------- masked mean subtraction ----------------
__global__ __launch_bounds__(256)
void meansub_kernel(float* __restrict__ out, const int* __restrict__ T) {
    const int b = blockIdx.x;
    __shared__ float part[3][NMEL];
    __shared__ float meanSh[NMEL];

    int maxT = T[0];
    for (int i = 1; i < BATCH; i++) maxT = max(maxT, T[i]);
    float ds = (float)maxT / (float)NMEL;          // f32, matches numpy
    int tb = (int)((float)T[b] / ds);              // trunc, matches astype(int32)

    const int q = threadIdx.x / NMEL;              // 0..2 active
    const int m = threadIdx.x - q * NMEL;
    float* pb = out + (size_t)b * NFR * NMEL;

    if (q < 3) {
        float s = 0.0f;
        for (int f = q; f < tb; f += 3) s += pb[(size_t)f * NMEL + m];
        part[q][m] = s;
    }
    __syncthreads();
    if (threadIdx.x < NMEL)
        meanSh[m] = (part[0][m] + part[1][m] + part[2][m]) / (float)max(tb, 1);
    __syncthreads();
    if (q < 3) {
        float mean = meanSh[m];
        for (int f = q; f < tb; f += 3) pb[(size_t)f * NMEL + m] -= mean;
    }
}

// ---------------- launcher ----------------
extern "C" void kernel_launch(void* const* d_in, const int* in_sizes, int n_in,
                              void* d_out, int out_size, void* d_ws, size_t ws_size,
                              hipStream_t stream) {
    const float* x    = (const float*)d_in[0];
    const int*   T    = (const int*)d_in[1];
    const float* norm = (const float*)d_in[2];
    float* out = (float*)d_out;

    init_tables_kernel<<<1, 256, 0, stream>>>();

    dim3 grid((NFR + NF - 1) / NF, BATCH);
    fbank_kernel<<<grid, 256, 0, stream>>>(x, norm, out);

    meansub_kernel<<<BATCH, 256, 0, stream>>>(out, T);
}

// Round 4
// 230.938 us; speedup vs baseline: 1.0067x; 1.0067x over previous
//
#include <hip/hip_runtime.h>
#include <hip/hip_bf16.h>

// ---------------- constants ----------------
#define BATCH   64
#define LSIG    240000
#define WIN     400
#define SHIFT   160
#define NFR     1498        // 1 + (240000-400)/160
#define NMEL    80
#define NBIN    200         // win/2 ; Nyquist bin has zero bank weight
#define NF      8           // frames per block
#define MAXW    14          // max nonzero mel-bank width (verified: max support = 14 bins)
#define SPECW   (NBIN + MAXW)   // 214

// S layout: [f][r][t2*2] with PADDED r-stride 44 floats.
// bank(rp*44 mod 32) = rp*12 mod 32 -> 11 rp values map to >=8 distinct bank-quads,
// worst 2-way (rp pairs {0,8},{1,9},{2,10}) -> ~free for b128 reads.
#define SSTR    44
#define SFR     (11 * SSTR)         // 484 floats per frame (16B-aligned: 484*4=1936)
#define S_TOT   (NF * SFR)          // 3872
#define WIN_OFF  S_TOT              // win[400]        (live: load..stage1)
#define TW1_OFF (S_TOT + 400)       // tw1[220][2]=440 (live: load..stage1)
#define XSEG_OFF (S_TOT + 840)      // xseg[1520]      (live: load..stage1)
#define SPEC_OFF S_TOT              // spec[NF*SPECW=1712] aliases win+tw1+xseg (stage2..3)
#define LDS_TOT (S_TOT + 840 + 1520)  // 6232 floats = 24.9 KB -> 6 blocks/CU

// ---------------- main fbank kernel (fully self-contained, no init) ----------------
__global__ __launch_bounds__(256, 6)
void fbank_kernel(const float* __restrict__ x, const float* __restrict__ norm,
                  float* __restrict__ out) {
    const int ft = blockIdx.x;
    const int b  = blockIdx.y;
    const int f0 = ft * NF;
    const int nf = min(NF, NFR - f0);
    const int tid = threadIdx.x;

    __shared__ __align__(16) float smem[LDS_TOT];
    float* Sb   = smem;
    float* winS = smem + WIN_OFF;
    float* tw1S = smem + TW1_OFF;
    float* xseg = smem + XSEG_OFF;
    float* spec = smem + SPEC_OFF;

    const float TWO_PI = 6.2831853071795864769f;

    // ---- global x load (issued first to hide HBM latency under table compute) ----
    const float* xb = x + (size_t)b * LSIG + (size_t)f0 * SHIFT;
    const int seglen = (nf - 1) * SHIFT + WIN;
    for (int i = tid; i < seglen; i += 256) xseg[i] = xb[i];

    // ---- tables in LDS via HW transcendentals (~3 sincos/thread) ----
    for (int j = tid; j < WIN; j += 256)
        winS[j] = 0.5f - 0.5f * __cosf(TWO_PI * (float)j / 399.0f);
    for (int i = tid; i < 220; i += 256) {
        int r = i / 20, t1 = i - r * 20;
        int j = (r * t1 * 20) % 400;                 // exact integer phase
        float th = (float)j * (-TWO_PI / 400.0f);
        tw1S[2 * i]     = __cosf(th);
        tw1S[2 * i + 1] = __sinf(th);
    }
    __syncthreads();

    // ---- stage 1: fused preemph+window + 20-pt real DFTs over t1, r=0..10 ----
    if (tid < nf * 20) {
        const int f = tid / 20, t2 = tid - f * 20;
        const float* xf = xseg + f * SHIFT;
        float yr[20];
#pragma unroll
        for (int t1 = 0; t1 < 20; t1++) {
            int t = t2 + 20 * t1;
            float xc = xf[t];
            float xp = xf[t > 0 ? t - 1 : 0];        // t==0: win==0 -> 0 anyway
            yr[t1] = (xc - 0.97f * xp) * winS[t];
        }
        float* Sf = Sb + f * SFR + t2 * 2;
#pragma unroll
        for (int r = 0; r <= 10; r++) {
            float ar = 0.0f, ai = 0.0f;
#pragma unroll
            for (int t1 = 0; t1 < 20; t1++) {
                float2 cs = *(const float2*)(tw1S + 2 * (r * 20 + t1));  // uniform -> broadcast
                ar = fmaf(yr[t1], cs.x, ar);
                ai = fmaf(yr[t1], cs.y, ai);
            }
            *(float2*)(Sf + r * SSTR) = make_float2(ar, ai);
        }
    }
    __syncthreads();

    // ---- stage 2: combine; thread=bin k; twiddles in 40 VGPRs via HW sincos ----
    {
        const int k = tid;
        if (k < NBIN) {
            int r = k % 20;
            int rp   = (r > 10) ? 20 - r : r;
            float sg = (r > 10) ? -1.0f : 1.0f;      // conj fold: power invariant
            float twc[20], tws[20];
#pragma unroll
            for (int t2 = 0; t2 < 20; t2++) {
                int j = (k * t2) % 400;
                float th = (float)j * (-TWO_PI / 400.0f);
                twc[t2] = __cosf(th);
                tws[t2] = __sinf(th) * sg;
            }
            for (int f = 0; f < nf; f++) {
                const float4* Sf = (const float4*)(Sb + f * SFR + rp * SSTR);
                float xr0 = 0.f, xi0 = 0.f, xr1 = 0.f, xi1 = 0.f;
#pragma unroll
                for (int q = 0; q < 10; q++) {
                    float4 v = Sf[q];                // re/im(t2=2q), re/im(t2=2q+1)
                    float c0 = twc[2 * q],     s0 = tws[2 * q];
                    float c1 = twc[2 * q + 1], s1 = tws[2 * q + 1];
                    xr0 = fmaf(c0, v.x, fmaf(-s0, v.y, xr0));
                    xi0 = fmaf(s0, v.x, fmaf(c0,  v.y, xi0));
                    xr1 = fmaf(c1, v.z, fmaf(-s1, v.w, xr1));
                    xi1 = fmaf(s1, v.z, fmaf(c1,  v.w, xi1));
                }
                float xr = xr0 + xr1, xi = xi0 + xi1;
                spec[f * SPECW + k] = fmaf(xr, xr, xi * xi);
            }
        } else if (k < SPECW) {
            for (int f = 0; f < NF; f++) spec[f * SPECW + k] = 0.0f;  // pad taps
        }
    }
    __syncthreads();

    // ---- stage 3: mel weights computed in-thread (f32 HW log/exp), 3 frames/thread ----
    if (tid < 240) {
        const int m = tid % 80;
        const int g = tid / 80;                      // 0..2
        const float mlow  = 1127.0f * __logf(1.0f + 20.0f / 700.0f);
        const float mhigh = 1127.0f * __logf(1.0f + 8000.0f / 700.0f);
        const float d     = (mhigh - mlow) * (1.0f / 81.0f);
        const float left  = mlow + (float)m * d;
        const float inv_d = 1.0f / d;
        float freq_left = 700.0f * (__expf(left * (1.0f / 1127.0f)) - 1.0f);
        int kstart = (int)floorf(freq_left * 0.025f) + 1;   // first bin right of left edge
        float w[MAXW];
#pragma unroll
        for (int j = 0; j < MAXW; j++) {
            float melk = 1127.0f * __logf(1.0f + (float)(kstart + j) * (40.0f / 700.0f));
            float up = (melk - left) * inv_d;
            float dn = 2.0f - up;                    // (right-melk)/d
            w[j] = fmaxf(0.0f, fminf(up, dn));       // boundary bins clamp to 0
        }
        const float nm = norm[m];
        for (int i = 0; i < 3; i++) {
            int f = g + 3 * i;
            if (f < nf) {
                const float* sp = spec + f * SPECW + kstart;
                float acc = 0.0f;
#pragma unroll
                for (int j = 0; j < MAXW; j++)
                    acc = fmaf(w[j], sp[j], acc);
                float mel = fmaxf(acc, 2.2204460492503131e-16f);
                out[((size_t)b * NFR + (f0 + f)) * NMEL + m] = __logf(mel) * nm;
            }
        }
    }
}

// ---------------- masked mean subtraction ----------------
__global__ __launch_bounds__(256)
void meansub_kernel(float* __restrict__ out, const int* __restrict__ T) {
    const int b = blockIdx.x;
    __shared__ float part[3][NMEL];
    __shared__ float meanSh[NMEL];

    int maxT = T[0];
    for (int i = 1; i < BATCH; i++) maxT = max(maxT, T[i]);
    float ds = (float)maxT / (float)NMEL;          // f32, matches numpy
    int tb = (int)((float)T[b] / ds);              // trunc, matches astype(int32)

    const int q = threadIdx.x / NMEL;              // 0..2 active
    const int m = threadIdx.x - q * NMEL;
    float* pb = out + (size_t)b * NFR * NMEL;

    if (q < 3) {
        float s = 0.0f;
        for (int f = q; f < tb; f += 3) s += pb[(size_t)f * NMEL + m];
        part[q][m] = s;
    }
    __syncthreads();
    if (threadIdx.x < NMEL)
        meanSh[m] = (part[0][m] + part[1][m] + part[2][m]) / (float)max(tb, 1);
    __syncthreads();
    if (q < 3) {
        float mean = meanSh[m];
        for (int f = q; f < tb; f += 3) pb[(size_t)f * NMEL + m] -= mean;
    }
}

// ---------------- launcher ----------------
extern "C" void kernel_launch(void* const* d_in, const int* in_sizes, int n_in,
                              void* d_out, int out_size, void* d_ws, size_t ws_size,
                              hipStream_t stream) {
    const float* x    = (const float*)d_in[0];
    const int*   T    = (const int*)d_in[1];
    const float* norm = (const float*)d_in[2];
    float* out = (float*)d_out;

    dim3 grid((NFR + NF - 1) / NF, BATCH);
    fbank_kernel<<<grid, 256, 0, stream>>>(x, norm, out);

    meansub_kernel<<<BATCH, 256, 0, stream>>>(out, T);
}

// Round 5
// 207.170 us; speedup vs baseline: 1.1222x; 1.1147x over previous
//
#include <hip/hip_runtime.h>

// ---------------- constants ----------------
#define BATCH   64
#define LSIG    240000
#define WIN     400
#define SHIFT   160
#define NFR     1498        // 1 + (240000-400)/160
#define NMEL    80
#define NBIN    200
#define NF      8           // frames per block
#define MAXW    14          // max nonzero mel-bank width
#define SPECW   (NBIN + MAXW)   // 214

// S layout: [f][rp][t2*2] padded r-stride 44 floats (bank-quad spread, worst 2-way)
#define SSTR    44
#define SFR     (11 * SSTR)          // 484
#define S_TOT   (NF * SFR)           // 3872
#define WIN_OFF  S_TOT               // win[400]   (live: load..stage1)
#define XSEG_OFF (S_TOT + WIN)       // xseg[1520] (live: load..stage1)
#define SPEC_OFF S_TOT               // spec[8*214=1712] aliases win+xseg (stage2..3)
#define LDS_TOT (S_TOT + WIN + 1520) // 5792 floats = 23.2 KB -> 6 blocks/CU

// ---------------- compile-time trig (f64 Taylor, exact quadrants) ----------------
constexpr double D_PI = 3.14159265358979323846264338327950288;
constexpr double tsin(double x){ double x2=x*x,t=x,s=x; for(int n=1;n<=13;++n){ t*=-x2/double((2*n)*(2*n+1)); s+=t;} return s; }
constexpr double tcos(double x){ double x2=x*x,t=1.0,s=1.0; for(int n=1;n<=13;++n){ t*=-x2/double((2*n-1)*(2*n)); s+=t;} return s; }
constexpr float cos400(int j){ int a=((j%400)+400)%400; int q=a/100, rem=a%100; double x=D_PI*(double)rem/200.0;
    double v = q==0? tcos(x) : q==1? -tsin(x) : q==2? -tcos(x) : tsin(x); return (float)v; }
constexpr float sin400(int j){ int a=((j%400)+400)%400; int q=a/100, rem=a%100; double x=D_PI*(double)rem/200.0;
    double v = q==0? tsin(x) : q==1? tcos(x) : q==2? -tsin(x) : -tcos(x); return (float)v; }

// stage-2 twiddle table: [q][u=m*11+rp][8] = (c1,s1) for t2=2q,2q+1 of bin k1=rp+20m,
// then (c2,s2f) for paired bin k2=(20-rp)+20m with conjugate sign PREFOLDED into s.
struct Tw2Tab {
    float v[10][110][8];
    constexpr Tw2Tab() : v{} {
        for (int q=0;q<10;++q) for (int u=0;u<110;++u) {
            int m=u/11, rp=u%11;
            int k1 = rp + 20*m;
            bool val2 = (rp>=1 && rp<=9);
            int k2 = val2 ? (20-rp+20*m) : k1;
            int ta=2*q, tb=2*q+1;
            v[q][u][0] = cos400(k1*ta); v[q][u][1] = -sin400(k1*ta);
            v[q][u][2] = cos400(k1*tb); v[q][u][3] = -sin400(k1*tb);
            v[q][u][4] = cos400(k2*ta); v[q][u][5] = val2 ?  sin400(k2*ta) : -sin400(k2*ta);
            v[q][u][6] = cos400(k2*tb); v[q][u][7] = val2 ?  sin400(k2*tb) : -sin400(k2*tb);
        }
    }
};
__device__ const Tw2Tab g_tw2{};

// ---------------- stage-1: 20-pt real DFT with LITERAL twiddles ----------------
template<int R, int T1> struct Mac1 {
    static __device__ __forceinline__ void go(const float* yr, float& ar, float& ai) {
        constexpr int j = ((R * T1) % 20) * 20;
        constexpr float c = cos400(j);
        constexpr float s = -sin400(j);          // imag of e^{-i*theta}
        float y = yr[T1];
        if constexpr (c == 1.0f)       ar += y;
        else if constexpr (c == -1.0f) ar -= y;
        else if constexpr (c == 0.0f)  {}
        else                           ar = fmaf(y, c, ar);
        if constexpr (s == 1.0f)       ai += y;
        else if constexpr (s == -1.0f) ai -= y;
        else if constexpr (s == 0.0f)  {}
        else                           ai = fmaf(y, s, ai);
        Mac1<R, T1 + 1>::go(yr, ar, ai);
    }
};
template<int R> struct Mac1<R, 20> { static __device__ __forceinline__ void go(const float*, float&, float&) {} };

template<int R> struct Dft1 {
    static __device__ __forceinline__ void go(const float* yr, float* Sf) {
        float ar = 0.0f, ai = 0.0f;
        Mac1<R, 0>::go(yr, ar, ai);
        *(float2*)(Sf + R * SSTR) = make_float2(ar, ai);
        Dft1<R + 1>::go(yr, Sf);
    }
};
template<> struct Dft1<11> { static __device__ __forceinline__ void go(const float*, float*) {} };

// ---------------- main fbank kernel ----------------
__global__ __launch_bounds__(256, 6)
void fbank_kernel(const float* __restrict__ x, const float* __restrict__ norm,
                  float* __restrict__ out) {
    const int ft = blockIdx.x;
    const int b  = blockIdx.y;
    const int f0 = ft * NF;
    const int nf = min(NF, NFR - f0);
    const int tid = threadIdx.x;

    __shared__ __align__(16) float smem[LDS_TOT];
    float* Sb   = smem;
    float* winS = smem + WIN_OFF;
    float* xseg = smem + XSEG_OFF;
    float* spec = smem + SPEC_OFF;

    // global x -> LDS (issued first), Hann window via HW cos (2/thread)
    const float* xb = x + (size_t)b * LSIG + (size_t)f0 * SHIFT;
    const int seglen = (nf - 1) * SHIFT + WIN;
    for (int i = tid; i < seglen; i += 256) xseg[i] = xb[i];
    const float TWO_PI = 6.28318530717958647693f;
    for (int j = tid; j < WIN; j += 256)
        winS[j] = 0.5f - 0.5f * __cosf(TWO_PI * (float)j / 399.0f);
    __syncthreads();

    // ---- stage 1: preemph+window fused, literal-twiddle 20-pt real DFTs ----
    if (tid < nf * 20) {
        const int f = tid / 20, t2 = tid - f * 20;
        const float* xf = xseg + f * SHIFT;
        float yr[20];
#pragma unroll
        for (int t1 = 0; t1 < 20; ++t1) {
            int t = t2 + 20 * t1;
            float xc = xf[t];
            float xp = xf[t > 0 ? t - 1 : 0];    // t==0: win==0 -> 0 anyway
            yr[t1] = (xc - 0.97f * xp) * winS[t];
        }
        Dft1<0>::go(yr, Sb + f * SFR + 2 * t2);
    }
    __syncthreads();

    // ---- stage 2: paired-bin combine; thread=(fhalf,m,rp); S reads broadcast ----
    if (tid < 220) {
        const int fhalf = tid / 110, u = tid - fhalf * 110;
        const int m = u / 11, rp = u - m * 11;
        const int k1 = rp + 20 * m;
        const int k2 = 20 - rp + 20 * m;
        const bool valid2 = (rp >= 1 && rp <= 9);
        float xr1[4], xi1[4], xr2[4], xi2[4];
#pragma unroll
        for (int fi = 0; fi < 4; ++fi) { xr1[fi]=0.f; xi1[fi]=0.f; xr2[fi]=0.f; xi2[fi]=0.f; }
        const float* Sbase = Sb + (fhalf * 4) * SFR + rp * SSTR;
#pragma unroll 2
        for (int q = 0; q < 10; ++q) {
            const float4 ta = *(const float4*)&g_tw2.v[q][u][0];
            const float4 tb = *(const float4*)&g_tw2.v[q][u][4];
#pragma unroll
            for (int fi = 0; fi < 4; ++fi) {
                float4 v = *(const float4*)(Sbase + fi * SFR + 4 * q);
                xr1[fi] = fmaf(ta.x, v.x, xr1[fi]); xr1[fi] = fmaf(-ta.y, v.y, xr1[fi]);
                xi1[fi] = fmaf(ta.y, v.x, xi1[fi]); xi1[fi] = fmaf( ta.x, v.y, xi1[fi]);
                xr1[fi] = fmaf(ta.z, v.z, xr1[fi]); xr1[fi] = fmaf(-ta.w, v.w, xr1[fi]);
                xi1[fi] = fmaf(ta.w, v.z, xi1[fi]); xi1[fi] = fmaf( ta.z, v.w, xi1[fi]);
                xr2[fi] = fmaf(tb.x, v.x, xr2[fi]); xr2[fi] = fmaf(-tb.y, v.y, xr2[fi]);
                xi2[fi] = fmaf(tb.y, v.x, xi2[fi]); xi2[fi] = fmaf( tb.x, v.y, xi2[fi]);
                xr2[fi] = fmaf(tb.z, v.z, xr2[fi]); xr2[fi] = fmaf(-tb.w, v.w, xr2[fi]);
                xi2[fi] = fmaf(tb.w, v.z, xi2[fi]); xi2[fi] = fmaf( tb.z, v.w, xi2[fi]);
            }
        }
#pragma unroll
        for (int fi = 0; fi < 4; ++fi) {
            int f = fhalf * 4 + fi;
            spec[f * SPECW + k1] = fmaf(xr1[fi], xr1[fi], xi1[fi] * xi1[fi]);
            if (valid2)
                spec[f * SPECW + k2] = fmaf(xr2[fi], xr2[fi], xi2[fi] * xi2[fi]);
        }
    } else if (tid < 220 + MAXW) {
        const int kp = NBIN + (tid - 220);       // zero pad taps
#pragma unroll
        for (int f = 0; f < NF; ++f) spec[f * SPECW + kp] = 0.0f;
    }
    __syncthreads();

    // ---- stage 3: in-thread mel weights (f32 HW log/exp), 3 frames/thread ----
    if (tid < 240) {
        const int m = tid % 80;
        const int g = tid / 80;                  // 0..2
        const float mlow  = 1127.0f * __logf(1.0f + 20.0f / 700.0f);
        const float mhigh = 1127.0f * __logf(1.0f + 8000.0f / 700.0f);
        const float d     = (mhigh - mlow) * (1.0f / 81.0f);
        const float left  = mlow + (float)m * d;
        const float inv_d = 1.0f / d;
        float freq_left = 700.0f * (__expf(left * (1.0f / 1127.0f)) - 1.0f);
        int kstart = (int)floorf(freq_left * 0.025f) + 1;
        float w[MAXW];
#pragma unroll
        for (int j = 0; j < MAXW; j++) {
            float melk = 1127.0f * __logf(1.0f + (float)(kstart + j) * (40.0f / 700.0f));
            float up = (melk - left) * inv_d;
            float dn = 2.0f - up;
            w[j] = fmaxf(0.0f, fminf(up, dn));
        }
        const float nm = norm[m];
        for (int i = 0; i < 3; i++) {
            int f = g + 3 * i;
            if (f < nf) {
                const float* sp = spec + f * SPECW + kstart;
                float acc = 0.0f;
#pragma unroll
                for (int j = 0; j < MAXW; j++)
                    acc = fmaf(w[j], sp[j], acc);
                float mel = fmaxf(acc, 2.2204460492503131e-16f);
                out[((size_t)b * NFR + (f0 + f)) * NMEL + m] = __logf(mel) * nm;
            }
        }
    }
}

// ---------------- masked mean subtraction ----------------
__global__ __launch_bounds__(256)
void meansub_kernel(float* __restrict__ out, const int* __restrict__ T) {
    const int b = blockIdx.x;
    __shared__ float part[3][NMEL];
    __shared__ float meanSh[NMEL];

    int maxT = T[0];
    for (int i = 1; i < BATCH; i++) maxT = max(maxT, T[i]);
    float ds = (float)maxT / (float)NMEL;        // f32, matches numpy
    int tb = (int)((float)T[b] / ds);            // trunc, matches astype(int32)

    const int q = threadIdx.x / NMEL;            // 0..2 active
    const int m = threadIdx.x - q * NMEL;
    float* pb = out + (size_t)b * NFR * NMEL;

    if (q < 3) {
        float s = 0.0f;
        for (int f = q; f < tb; f += 3) s += pb[(size_t)f * NMEL + m];
        part[q][m] = s;
    }
    __syncthreads();
    if (threadIdx.x < NMEL)
        meanSh[m] = (part[0][m] + part[1][m] + part[2][m]) / (float)max(tb, 1);
    __syncthreads();
    if (q < 3) {
        float mean = meanSh[m];
        for (int f = q; f < tb; f += 3) pb[(size_t)f * NMEL + m] -= mean;
    }
}

// ---------------- launcher ----------------
extern "C" void kernel_launch(void* const* d_in, const int* in_sizes, int n_in,
                              void* d_out, int out_size, void* d_ws, size_t ws_size,
                              hipStream_t stream) {
    const float* x    = (const float*)d_in[0];
    const int*   T    = (const int*)d_in[1];
    const float* norm = (const float*)d_in[2];
    float* out = (float*)d_out;

    dim3 grid((NFR + NF - 1) / NF, BATCH);
    fbank_kernel<<<grid, 256, 0, stream>>>(x, norm, out);

    meansub_kernel<<<BATCH, 256, 0, stream>>>(out, T);
}

// Round 8
// 202.464 us; speedup vs baseline: 1.1482x; 1.0232x over previous
//
#include <hip/hip_runtime.h>

// ---------------- constants ----------------
#define BATCH   64
#define LSIG    240000
#define WIN     400
#define SHIFT   160
#define NFR     1498        // 1 + (240000-400)/160
#define NMEL    80
#define NBIN    200
#define NF      8           // frames per block
#define MAXW    14          // max nonzero mel-bank width
#define SPECW   (NBIN + MAXW)   // 214

// S layout: [f][rp][t2*2], r-stride 44 floats (bank-quad spread, worst ~2-way)
#define SSTR    44
#define SFR     484                  // frame stride (11*44), f*484 = 4f mod 32 stagger
#define S_TOT   (NF * SFR)           // 3872
#define XSEG_OFF S_TOT               // xseg[1520] (live: load..stage1)
#define SPEC_OFF S_TOT               // spec[8*214=1712] aliases xseg (stage2..3)
#define LDS_TOT (S_TOT + NF * SPECW) // 5584 floats = 22336 B -> 7 blocks/CU

// ---------------- compile-time trig (f64 Taylor, exact quadrants) ----------------
constexpr double D_PI = 3.14159265358979323846264338327950288;
constexpr double tsin(double x){ double x2=x*x,t=x,s=x; for(int n=1;n<=13;++n){ t*=-x2/double((2*n)*(2*n+1)); s+=t;} return s; }
constexpr double tcos(double x){ double x2=x*x,t=1.0,s=1.0; for(int n=1;n<=13;++n){ t*=-x2/double((2*n-1)*(2*n)); s+=t;} return s; }
constexpr float cos400(int j){ int a=((j%400)+400)%400; int q=a/100, rem=a%100; double x=D_PI*(double)rem/200.0;
    double v = q==0? tcos(x) : q==1? -tsin(x) : q==2? -tcos(x) : tsin(x); return (float)v; }
constexpr float sin400(int j){ int a=((j%400)+400)%400; int q=a/100, rem=a%100; double x=D_PI*(double)rem/200.0;
    double v = q==0? tsin(x) : q==1? tcos(x) : q==2? -tsin(x) : -tcos(x); return (float)v; }

// stage-2 twiddles per u=(m5,rp):
// [0..7]   2a k1-class: (c, s=-sin) for t2b=1..4   (e^{-2pi i k1 t2b/100})
// [8..15]  2a k2-class
// [16..21] 2b k1: (c, s) for t2a=1..3              (e^{-2pi i k1 t2a/400})
// [22..27] 2b k2
struct Tw3 {
    float v[55][32];
    constexpr Tw3() : v{} {
        for (int m5=0;m5<5;++m5) for (int rp=0;rp<11;++rp) {
            int u = m5*11+rp;
            int k1 = rp + 20*m5;
            int k2 = (20-rp) + 20*m5;
            for (int tb=1; tb<=4; ++tb) {
                v[u][2*(tb-1)]     =  cos400(4*k1*tb);
                v[u][2*(tb-1)+1]   = -sin400(4*k1*tb);
                v[u][8+2*(tb-1)]   =  cos400(4*k2*tb);
                v[u][8+2*(tb-1)+1] = -sin400(4*k2*tb);
            }
            for (int ta=1; ta<=3; ++ta) {
                v[u][16+2*(ta-1)]   =  cos400(k1*ta);
                v[u][16+2*(ta-1)+1] = -sin400(k1*ta);
                v[u][22+2*(ta-1)]   =  cos400(k2*ta);
                v[u][22+2*(ta-1)+1] = -sin400(k2*ta);
            }
        }
    }
};
__device__ const Tw3 g_tw3{};

// ---------------- stage-1: t1-outer, 22 accumulators, literal twiddles ----------------
template<int T1, int R> struct Mac1R {
    static __device__ __forceinline__ void go(float y, float* ar, float* ai) {
        constexpr int j = ((R * T1) % 20) * 20;
        constexpr float c =  cos400(j);
        constexpr float s = -sin400(j);
        if constexpr (c == 1.0f)       ar[R] += y;
        else if constexpr (c == -1.0f) ar[R] -= y;
        else if constexpr (c != 0.0f)  ar[R] = fmaf(y, c, ar[R]);
        if constexpr (s == 1.0f)       ai[R] += y;
        else if constexpr (s == -1.0f) ai[R] -= y;
        else if constexpr (s != 0.0f)  ai[R] = fmaf(y, s, ai[R]);
        Mac1R<T1, R + 1>::go(y, ar, ai);
    }
};
template<int T1> struct Mac1R<T1, 11> { static __device__ __forceinline__ void go(float, float*, float*) {} };

template<int T1> struct Col {
    static __device__ __forceinline__ void go(const float* xf, int t2, const float* wreg,
                                              float* ar, float* ai) {
        int t = t2 + 20 * T1;
        int tp = t - 1;
        if constexpr (T1 == 0) tp = max(tp, 0);   // t==0: win==0 -> y=0 anyway
        float y = (xf[t] - 0.97f * xf[tp]) * wreg[T1];
        Mac1R<T1, 0>::go(y, ar, ai);
        Col<T1 + 1>::go(xf, t2, wreg, ar, ai);
    }
};
template<> struct Col<20> { static __device__ __forceinline__ void go(const float*, int, const float*, float*, float*) {} };

// ---------------- main fbank kernel ----------------
__global__ __launch_bounds__(256, 6)
void fbank_kernel(const float* __restrict__ x, const float* __restrict__ norm,
                  float* __restrict__ out) {
    const int ft = blockIdx.x;
    const int b  = blockIdx.y;
    const int f0 = ft * NF;
    const int nf = min(NF, NFR - f0);
    const int tid = threadIdx.x;

    __shared__ __align__(16) float smem[LDS_TOT];
    float* Sb   = smem;
    float* xseg = smem + XSEG_OFF;
    float* spec = smem + SPEC_OFF;

    // global x -> LDS
    const float* xb = x + (size_t)b * LSIG + (size_t)f0 * SHIFT;
    const int seglen = (nf - 1) * SHIFT + WIN;
    for (int i = tid; i < seglen; i += 256) xseg[i] = xb[i];

    // per-thread Hann window registers (overlaps load latency; no LDS)
    const float TWO_PI = 6.28318530717958647693f;
    float wreg[20];
    {
        const int t2w = tid % 20;
#pragma unroll
        for (int t1 = 0; t1 < 20; ++t1)
            wreg[t1] = 0.5f - 0.5f * __cosf(TWO_PI * (float)(t2w + 20 * t1) / 399.0f);
    }
    __syncthreads();

    // ---- stage 1: preemph+window fused, literal-twiddle 20-pt real DFTs, t1-outer ----
    if (tid < nf * 20) {
        const int f = tid / 20, t2 = tid - f * 20;
        float ar[11], ai[11];
#pragma unroll
        for (int r = 0; r < 11; ++r) { ar[r] = 0.0f; ai[r] = 0.0f; }
        Col<0>::go(xseg + f * SHIFT, t2, wreg, ar, ai);
        float* Sf = Sb + f * SFR + 2 * t2;
#pragma unroll
        for (int r = 0; r < 11; ++r)
            *(float2*)(Sf + r * SSTR) = make_float2(ar[r], ai[r]);
    }
    __syncthreads();

    // ---- stage 2: 3-stage combine (radix-5 then radix-4), 4 bins/thread/frame ----
    if (tid < 220) {
        const int fquad = tid / 55, u = tid - fquad * 55;
        const int m5 = u / 11, rp = u - m5 * 11;
        const int k1 = rp + 20 * m5;
        const int k2 = (20 - rp) + 20 * m5;
        const bool valid2 = (rp >= 1 && rp <= 9);

        // twiddles -> registers (7 float4 = 28 floats)
        const float4* tp4 = (const float4*)&g_tw3.v[u][0];
        float4 w0 = tp4[0], w1 = tp4[1], w2 = tp4[2], w3 = tp4[3];
        float4 w4 = tp4[4], w5 = tp4[5], w6 = tp4[6];
        float t1c[5], t1s[5], t2c[5], t2s[5];
        t1c[1]=w0.x; t1s[1]=w0.y; t1c[2]=w0.z; t1s[2]=w0.w;
        t1c[3]=w1.x; t1s[3]=w1.y; t1c[4]=w1.z; t1s[4]=w1.w;
        t2c[1]=w2.x; t2s[1]=w2.y; t2c[2]=w2.z; t2s[2]=w2.w;
        t2c[3]=w3.x; t2s[3]=w3.y; t2c[4]=w3.z; t2s[4]=w3.w;
        float b1c[4], b1s[4], b2c[4], b2s[4];
        b1c[1]=w4.x; b1s[1]=w4.y; b1c[2]=w4.z; b1s[2]=w4.w;
        b1c[3]=w5.x; b1s[3]=w5.y;
        b2c[1]=w5.z; b2s[1]=w5.w; b2c[2]=w6.x; b2s[2]=w6.y;
        b2c[3]=w6.z; b2s[3]=w6.w;

#pragma unroll
        for (int fi = 0; fi < 2; ++fi) {
            const int f = 2 * fquad + fi;
            if (f < nf) {
                const float* Sf = Sb + f * SFR + rp * SSTR;
                float4 v0 = *(const float4*)(Sf);
                float4 v1 = *(const float4*)(Sf + 4);
                float U1r[4], U1i[4], U2r[4], U2i[4];
                U1r[0]=v0.x; U1i[0]=v0.y; U2r[0]=v0.x; U2i[0]=-v0.y;
                U1r[1]=v0.z; U1i[1]=v0.w; U2r[1]=v0.z; U2i[1]=-v0.w;
                U1r[2]=v1.x; U1i[2]=v1.y; U2r[2]=v1.x; U2i[2]=-v1.y;
                U1r[3]=v1.z; U1i[3]=v1.w; U2r[3]=v1.z; U2i[3]=-v1.w;
#pragma unroll
                for (int q = 2; q < 10; ++q) {
                    float4 v = *(const float4*)(Sf + 4 * q);
                    const int tb = q >> 1;             // 1..4
                    const int ta = (q & 1) * 2;        // 0 or 2
                    float c = t1c[tb], s = t1s[tb], c2 = t2c[tb], s2 = t2s[tb];
                    U1r[ta]   = fmaf(c,  v.x, fmaf(-s,  v.y, U1r[ta]));
                    U1i[ta]   = fmaf(s,  v.x, fmaf( c,  v.y, U1i[ta]));
                    U2r[ta]   = fmaf(c2, v.x, fmaf( s2, v.y, U2r[ta]));
                    U2i[ta]   = fmaf(s2, v.x, fmaf(-c2, v.y, U2i[ta]));
                    U1r[ta+1] = fmaf(c,  v.z, fmaf(-s,  v.w, U1r[ta+1]));
                    U1i[ta+1] = fmaf(s,  v.z, fmaf( c,  v.w, U1i[ta+1]));
                    U2r[ta+1] = fmaf(c2, v.z, fmaf( s2, v.w, U2r[ta+1]));
                    U2i[ta+1] = fmaf(s2, v.z, fmaf(-c2, v.w, U2i[ta+1]));
                }
                // 2b, k1 family: bins k1 and k1+100 share products (x(-i)^t2a)
                {
                    float p1r = fmaf(b1c[1],U1r[1], -b1s[1]*U1i[1]);
                    float p1i = fmaf(b1s[1],U1r[1],  b1c[1]*U1i[1]);
                    float p2r = fmaf(b1c[2],U1r[2], -b1s[2]*U1i[2]);
                    float p2i = fmaf(b1s[2],U1r[2],  b1c[2]*U1i[2]);
                    float p3r = fmaf(b1c[3],U1r[3], -b1s[3]*U1i[3]);
                    float p3i = fmaf(b1s[3],U1r[3],  b1c[3]*U1i[3]);
                    float Xr = (U1r[0] + p1r) + (p2r + p3r);
                    float Xi = (U1i[0] + p1i) + (p2i + p3i);
                    float Yr = (U1r[0] + p1i) - (p2r + p3i);
                    float Yi = (U1i[0] - p1r) + (p3r - p2i);
                    spec[f * SPECW + k1]       = fmaf(Xr, Xr, Xi * Xi);
                    spec[f * SPECW + k1 + 100] = fmaf(Yr, Yr, Yi * Yi);
                }
                // 2b, k2 family (conjugated S path)
                {
                    float p1r = fmaf(b2c[1],U2r[1], -b2s[1]*U2i[1]);
                    float p1i = fmaf(b2s[1],U2r[1],  b2c[1]*U2i[1]);
                    float p2r = fmaf(b2c[2],U2r[2], -b2s[2]*U2i[2]);
                    float p2i = fmaf(b2s[2],U2r[2],  b2c[2]*U2i[2]);
                    float p3r = fmaf(b2c[3],U2r[3], -b2s[3]*U2i[3]);
                    float p3i = fmaf(b2s[3],U2r[3],  b2c[3]*U2i[3]);
                    float Xr = (U2r[0] + p1r) + (p2r + p3r);
                    float Xi = (U2i[0] + p1i) + (p2i + p3i);
                    float Yr = (U2r[0] + p1i) - (p2r + p3i);
                    float Yi = (U2i[0] - p1r) + (p3r - p2i);
                    if (valid2) {
                        spec[f * SPECW + k2]       = fmaf(Xr, Xr, Xi * Xi);
                        spec[f * SPECW + k2 + 100] = fmaf(Yr, Yr, Yi * Yi);
                    }
                }
            }
        }
    } else if (tid < 220 + MAXW) {
        const int kp = NBIN + (tid - 220);           // zero pad taps
#pragma unroll
        for (int f = 0; f < NF; ++f) spec[f * SPECW + kp] = 0.0f;
    }
    __syncthreads();

    // ---- stage 3: in-thread mel weights (f32 HW log/exp), 3 frames/thread ----
    if (tid < 240) {
        const int m = tid % 80;
        const int g = tid / 80;                      // 0..2
        const float mlow  = 1127.0f * __logf(1.0f + 20.0f / 700.0f);
        const float mhigh = 1127.0f * __logf(1.0f + 8000.0f / 700.0f);
        const float d     = (mhigh - mlow) * (1.0f / 81.0f);
        const float left  = mlow + (float)m * d;
        const float inv_d = 1.0f / d;
        float freq_left = 700.0f * (__expf(left * (1.0f / 1127.0f)) - 1.0f);
        int kstart = (int)floorf(freq_left * 0.025f) + 1;
        float w[MAXW];
#pragma unroll
        for (int j = 0; j < MAXW; j++) {
            float melk = 1127.0f * __logf(1.0f + (float)(kstart + j) * (40.0f / 700.0f));
            float up = (melk - left) * inv_d;
            float dn = 2.0f - up;
            w[j] = fmaxf(0.0f, fminf(up, dn));
        }
        const float nm = norm[m];
        for (int i = 0; i < 3; i++) {
            int f = g + 3 * i;
            if (f < nf) {
                const float* sp = spec + f * SPECW + kstart;
                float acc = 0.0f;
#pragma unroll
                for (int j = 0; j < MAXW; j++)
                    acc = fmaf(w[j], sp[j], acc);
                float mel = fmaxf(acc, 2.2204460492503131e-16f);
                out[((size_t)b * NFR + (f0 + f)) * NMEL + m] = __logf(mel) * nm;
            }
        }
    }
}

// ---------------- masked mean subtraction ----------------
__global__ __launch_bounds__(256)
void meansub_kernel(float* __restrict__ out, const int* __restrict__ T) {
    const int b = blockIdx.x;
    __shared__ float part[3][NMEL];
    __shared__ float meanSh[NMEL];

    int maxT = T[0];
    for (int i = 1; i < BATCH; i++) maxT = max(maxT, T[i]);
    float ds = (float)maxT / (float)NMEL;        // f32, matches numpy
    int tb = (int)((float)T[b] / ds);            // trunc, matches astype(int32)

    const int q = threadIdx.x / NMEL;            // 0..2 active
    const int m = threadIdx.x - q * NMEL;
    float* pb = out + (size_t)b * NFR * NMEL;

    if (q < 3) {
        float s = 0.0f;
        for (int f = q; f < tb; f += 3) s += pb[(size_t)f * NMEL + m];
        part[q][m] = s;
    }
    __syncthreads();
    if (threadIdx.x < NMEL)
        meanSh[m] = (part[0][m] + part[1][m] + part[2][m]) / (float)max(tb, 1);
    __syncthreads();
    if (q < 3) {
        float mean = meanSh[m];
        for (int f = q; f < tb; f += 3) pb[(size_t)f * NMEL + m] -= mean;
    }
}

// ---------------- launcher ----------------
extern "C" void kernel_launch(void* const* d_in, const int* in_sizes, int n_in,
                              void* d_out, int out_size, void* d_ws, size_t ws_size,
                              hipStream_t stream) {
    const float* x    = (const float*)d_in[0];
    const int*   T    = (const int*)d_in[1];
    const float* norm = (const float*)d_in[2];
    float* out = (float*)d_out;

    dim3 grid((NFR + NF - 1) / NF, BATCH);
    fbank_kernel<<<grid, 256, 0, stream>>>(x, norm, out);

    meansub_kernel<<<BATCH, 256, 0, stream>>>(out, T);
}